// Round 3
// baseline (320.438 us; speedup 1.0000x reference)
//
#include <hip/hip_runtime.h>

// DCGRU cell, MI355X.
//   Diffusion intermediates TRANSPOSED: XT[col = f*64+b][node n] in bf16.
//   Chebyshev recursion FOLDED: T_z = 2*S_z^2 - I precomputed (sq_gemm), so
//   each gconv is ONE launch: [S0;T0;S1;T1](4096x1024) @ X(1024x4224).
//   gconv_gemm/sq_gemm: 128x128 tile, BK=32, FOUR LDS buffers (64KB,
//     2 blocks/CU), depth-3 prefetch, raw s_barrier + counted vmcnt(8)
//     (never 0 in main loop). XOR swizzle via pre-swizzled GLOBAL source
//     (global_load_lds writes linearly). XCD-bijective block swizzle.
//   proj1/proj2: A staged in LDS as [n][kp] row stride 360 (720B: 5n mod 8
//     bijective -> conflict-free ds_read_b128 A-frags, ONE per 32-k step).
//     B-frags straight from global Wt (L2-hot). d_out doubles as u-buffer.

typedef unsigned short u16;
typedef unsigned int u32;
typedef short s16x8 __attribute__((ext_vector_type(8)));
typedef float f32x4 __attribute__((ext_vector_type(4)));
typedef u16 u16x4 __attribute__((ext_vector_type(4)));

#define NN 1024
#define NB 64
#define NF 66
#define NCOLS 4224  // NF*NB
#define KPAD 352    // 330 padded to 11*32
#define ASTRIDE 360 // proj A-LDS row stride in u16 (720B, 5n%8 bijection)

__device__ __forceinline__ u16 f2bf(float f) {
  u32 u = __builtin_bit_cast(u32, f);
  u = (u + 0x7fffu + ((u >> 16) & 1u)) >> 16;  // RNE
  return (u16)u;
}
__device__ __forceinline__ float bf2f(u16 h) {
  u32 u = ((u32)h) << 16;
  return __builtin_bit_cast(float, u);
}

__device__ __forceinline__ void gload16(const void* g, void* l) {
  __builtin_amdgcn_global_load_lds(
      (const __attribute__((address_space(1))) u32*)g,
      (__attribute__((address_space(3))) u32*)l, 16, 0, 0);
}

// counted-vmcnt barrier: own oldest loads landed -> barrier -> fence reads
#define CHEB_WAIT(N)                                      \
  do {                                                    \
    asm volatile("s_waitcnt vmcnt(" #N ")" ::: "memory"); \
    __builtin_amdgcn_s_barrier();                         \
    asm volatile("" ::: "memory");                        \
  } while (0)

// ---------------- pack kernels ----------------

// 64x64 f32 tiles: write bf16 S_z into Acat S-rows (z*2048 base) and bf16
// transpose into ST_z (for sq_gemm's A operand).
__global__ __launch_bounds__(256) void pack_supports(
    const float* __restrict__ s0, const float* __restrict__ s1,
    u16* __restrict__ Acat, u16* __restrict__ ST0, u16* __restrict__ ST1) {
  __shared__ float tile[64][65];
  const int z = blockIdx.y;
  const float* S = z ? s1 : s0;
  u16* ST = z ? ST1 : ST0;
  const int r0 = (blockIdx.x >> 4) * 64, c0 = (blockIdx.x & 15) * 64;
  const int t = threadIdx.x;
  const size_t sbase = (size_t)z * 2048 * NN;
  int cc4 = (t & 15) * 4, rr = t >> 4;
#pragma unroll
  for (int p = 0; p < 4; p++) {
    int r = p * 16 + rr;
    f32x4 v = *(const f32x4*)(S + (size_t)(r0 + r) * NN + c0 + cc4);
    tile[r][cc4] = v.x; tile[r][cc4 + 1] = v.y;
    tile[r][cc4 + 2] = v.z; tile[r][cc4 + 3] = v.w;
    u16x4 o;
    o.x = f2bf(v.x); o.y = f2bf(v.y); o.z = f2bf(v.z); o.w = f2bf(v.w);
    *(u16x4*)&Acat[sbase + (size_t)(r0 + r) * NN + c0 + cc4] = o;
  }
  __syncthreads();
  int rr4 = (t & 15) * 4, cc = t >> 4;
#pragma unroll
  for (int p = 0; p < 4; p++) {
    int c = p * 16 + cc;
    u16x4 o;
    o.x = f2bf(tile[rr4][c]);     o.y = f2bf(tile[rr4 + 1][c]);
    o.z = f2bf(tile[rr4 + 2][c]); o.w = f2bf(tile[rr4 + 3][c]);
    *(u16x4*)&ST[(size_t)(c0 + c) * NN + r0 + rr4] = o;
  }
}

// Wt[o][kp] = W[f*5+m][o], kp = m*66+f, zero-padded kp in [330,352)
__global__ __launch_bounds__(64) void pack_w(
    const float* __restrict__ W, u16* __restrict__ Wt, int ldo) {
  int o = blockIdx.y;
  int kp = blockIdx.x * 64 + threadIdx.x;
  if (kp >= KPAD) return;
  float v = 0.f;
  if (kp < 330) {
    int m = kp / 66;
    int f = kp - m * 66;
    v = W[(f * 5 + m) * ldo + o];
  }
  Wt[(size_t)o * KPAD + kp] = f2bf(v);
}

// rows f=0,1 of X0^T and X0'^T: X0T[f*64+b][n] = inputs[b][2n+f]
__global__ __launch_bounds__(256) void pack_x0_inputs(
    const float* __restrict__ inp, u16* __restrict__ x0t, u16* __restrict__ x0pt) {
  int b = blockIdx.x, t = threadIdx.x;
  int n4 = t * 4;
  const float* src = inp + b * 2048 + n4 * 2;
  f32x4 a = *(const f32x4*)src;
  f32x4 c = *(const f32x4*)(src + 4);
  u16x4 r0, r1;
  r0.x = f2bf(a.x); r0.y = f2bf(a.z); r0.z = f2bf(c.x); r0.w = f2bf(c.z);  // f=0
  r1.x = f2bf(a.y); r1.y = f2bf(a.w); r1.z = f2bf(c.y); r1.w = f2bf(c.w);  // f=1
  size_t o0 = (size_t)(b)*NN + n4;
  size_t o1 = (size_t)(64 + b) * NN + n4;
  *(u16x4*)(x0t + o0) = r0;  *(u16x4*)(x0t + o1) = r1;
  *(u16x4*)(x0pt + o0) = r0; *(u16x4*)(x0pt + o1) = r1;
}

// rows f>=2 of X0^T: X0T[(2+u)*64+b][n] = hx[b][n*64+u]  (64x64 LDS transpose tiles)
__global__ __launch_bounds__(256) void pack_x0_hx(
    const float* __restrict__ hx, u16* __restrict__ x0t) {
  __shared__ float tile[64][65];
  int n0 = blockIdx.x * 64, b = blockIdx.y, t = threadIdx.x;
  int u4 = (t & 15) * 4, r0 = t >> 4;
#pragma unroll
  for (int p = 0; p < 4; p++) {
    int row = p * 16 + r0;
    f32x4 v = *(const f32x4*)(hx + ((size_t)b << 16) + (size_t)(n0 + row) * 64 + u4);
    tile[row][u4] = v.x; tile[row][u4 + 1] = v.y;
    tile[row][u4 + 2] = v.z; tile[row][u4 + 3] = v.w;
  }
  __syncthreads();
  int n4 = (t & 15) * 4, uu0 = t >> 4;
#pragma unroll
  for (int p = 0; p < 4; p++) {
    int u = p * 16 + uu0;
    u16x4 o;
    o.x = f2bf(tile[n4][u]);     o.y = f2bf(tile[n4 + 1][u]);
    o.z = f2bf(tile[n4 + 2][u]); o.w = f2bf(tile[n4 + 3][u]);
    *(u16x4*)&x0t[(size_t)((2 + u) * 64 + b) * NN + n0 + n4] = o;
  }
}

// ---------------- pipelined 128x128xK=1024 GEMM core ----------------
// A,B row-major-over-K bf16, K=1024, BK=32, 4 LDS buffers, depth-3 prefetch.
// LDS row = 4 chunks of 16B; logical chunk c of row r at physical c^((r>>1)&3)
// (pre-swizzled global source; global_load_lds writes linearly).

__device__ __forceinline__ void gemm128_pipe(
    const u16* pAr, const u16* pBr,  // per-lane global src (row & swizzle applied)
    u16* As, u16* Bs,                // 4 buffers each, 128*32 u16 per buffer
    int w, int lane, f32x4 acc[4][4]) {
  const int db0 = (w * 32) * 32;       // wave-uniform LDS dest (u16)
  const int db1 = (w * 32 + 16) * 32;
  const u16* pA0 = pAr; const u16* pA1 = pAr + (size_t)16 * NN;
  const u16* pB0 = pBr; const u16* pB1 = pBr + (size_t)16 * NN;
  const int wm = (w >> 1) * 64;
  const int wn = (w & 1) * 64;
  const int fr = lane & 15;
  const int q = lane >> 4;
  const int fo = (q ^ ((fr >> 1) & 3)) * 8;  // frag chunk un-swizzle

  auto stage = [&](int buf) {
    u16* dA = As + buf * (128 * 32);
    u16* dB = Bs + buf * (128 * 32);
    gload16(pA0, dA + db0);
    gload16(pA1, dA + db1);
    gload16(pB0, dB + db0);
    gload16(pB1, dB + db1);
    pA0 += 32; pA1 += 32; pB0 += 32; pB1 += 32;
  };
  auto compute = [&](int buf) {
    const u16* cA = As + buf * (128 * 32);
    const u16* cB = Bs + buf * (128 * 32);
    s16x8 af[4], bfr[4];
#pragma unroll
    for (int i = 0; i < 4; i++)
      af[i] = *(const s16x8*)&cA[(wm + i * 16 + fr) * 32 + fo];
#pragma unroll
    for (int j = 0; j < 4; j++)
      bfr[j] = *(const s16x8*)&cB[(wn + j * 16 + fr) * 32 + fo];
#pragma unroll
    for (int i = 0; i < 4; i++)
#pragma unroll
      for (int j = 0; j < 4; j++)
        acc[i][j] = __builtin_amdgcn_mfma_f32_16x16x32_bf16(af[i], bfr[j], acc[i][j], 0, 0, 0);
  };

  stage(0); stage(1); stage(2);  // t0,t1,t2 in flight (12 loads)
#pragma unroll 1
  for (int it = 0; it < 7; it++) {  // t = 4*it + {0..3}, t in [0,28)
    CHEB_WAIT(8); stage(3); compute(0);
    CHEB_WAIT(8); stage(0); compute(1);
    CHEB_WAIT(8); stage(1); compute(2);
    CHEB_WAIT(8); stage(2); compute(3);
  }
  CHEB_WAIT(8); stage(3); compute(0);  // t=28, stage t=31
  CHEB_WAIT(8); compute(1);            // t=29
  CHEB_WAIT(4); compute(2);            // t=30
  CHEB_WAIT(0); compute(3);            // t=31
}

// gconv GEMM: C = Acat[4096x1024] @ X[1024 x 4224cols], outputs split by mat:
//   md 0->X1 (S0*X), 1->X2 (T0*X), 2->X3 (S1*X), 3->X4 (T1*X); Xo[col][node].
__global__ __launch_bounds__(256, 2) void gconv_gemm(
    const u16* __restrict__ Acat, const u16* __restrict__ Bx,
    u16* __restrict__ X1, u16* __restrict__ X2,
    u16* __restrict__ X3, u16* __restrict__ X4) {
  __shared__ u16 As[4][128 * 32];
  __shared__ u16 Bs[4][128 * 32];
  const int t = threadIdx.x;
  const int lane = t & 63;
  const int w = t >> 6;

  // XCD swizzle (1056 = 8*132): each XCD owns 4 m-tiles x all 33 n-tiles.
  const int lid = blockIdx.x;
  const int work = (lid & 7) * 132 + (lid >> 3);
  const int mt = work / 33;   // 0..31: mat = mt>>3, node-block = mt&7
  const int nt = work % 33;   // col tile

  const int rl = lane >> 2;
  const int swz = ((lane & 3) ^ ((lane >> 3) & 3)) * 8;
  const u16* pAr = Acat + (size_t)(mt * 128 + w * 32 + rl) * NN + swz;
  const u16* pBr = Bx + (size_t)(nt * 128 + w * 32 + rl) * NN + swz;

  f32x4 acc[4][4];
#pragma unroll
  for (int i = 0; i < 4; i++)
#pragma unroll
    for (int j = 0; j < 4; j++) acc[i][j] = f32x4{0.f, 0.f, 0.f, 0.f};

  gemm128_pipe(pAr, pBr, &As[0][0], &Bs[0][0], w, lane, acc);

  const int md = mt >> 3;
  u16* Xo = md == 0 ? X1 : md == 1 ? X2 : md == 2 ? X3 : X4;
  const int m0 = (mt & 7) * 128;
  const int n0 = nt * 128;
  const int wm = (w >> 1) * 64;
  const int wn = (w & 1) * 64;
  const int fr = lane & 15;
  const int nr0 = (lane >> 4) << 2;
  // C/D layout: col = lane&15, row = (lane>>4)*4 + reg
#pragma unroll
  for (int i = 0; i < 4; i++) {
    const int node = m0 + wm + i * 16 + nr0;
#pragma unroll
    for (int j = 0; j < 4; j++) {
      const int colg = n0 + wn + j * 16 + fr;
      f32x4 c = acc[i][j];
      u16x4 o;
      o.x = f2bf(c.x); o.y = f2bf(c.y); o.z = f2bf(c.z); o.w = f2bf(c.w);
      *(u16x4*)&Xo[(size_t)colg * NN + node] = o;
    }
  }
}

// T_z = 2*S_z^2 - I into Acat T-rows. Computes C[m][n] = ST_z[m]|Sb_z[n] dot
// = S^2[n][m]; writes Acat[Tbase+n][m] = 2*C - (m==n) (row-major T, coalesced).
__global__ __launch_bounds__(256, 2) void sq_gemm(
    const u16* __restrict__ ST0, const u16* __restrict__ ST1, u16* Acat) {
  __shared__ u16 As[4][128 * 32];
  __shared__ u16 Bs[4][128 * 32];
  const int t = threadIdx.x;
  const int lane = t & 63;
  const int w = t >> 6;

  const int lid = blockIdx.x;                  // 128 blocks
  const int work = (lid & 7) * 16 + (lid >> 3);
  const int z = work >> 6;
  const int rr = work & 63;
  const int mtile = rr >> 3, ntile = rr & 7;

  const u16* A = z ? ST1 : ST0;
  const u16* B = Acat + (size_t)(z * 2048) * NN;  // S_z rows of Acat

  const int rl = lane >> 2;
  const int swz = ((lane & 3) ^ ((lane >> 3) & 3)) * 8;
  const u16* pAr = A + (size_t)(mtile * 128 + w * 32 + rl) * NN + swz;
  const u16* pBr = B + (size_t)(ntile * 128 + w * 32 + rl) * NN + swz;

  f32x4 acc[4][4];
#pragma unroll
  for (int i = 0; i < 4; i++)
#pragma unroll
    for (int j = 0; j < 4; j++) acc[i][j] = f32x4{0.f, 0.f, 0.f, 0.f};

  gemm128_pipe(pAr, pBr, &As[0][0], &Bs[0][0], w, lane, acc);

  const size_t tbase = z ? 3072 : 1024;
  const int wm = (w >> 1) * 64;
  const int wn = (w & 1) * 64;
  const int fr = lane & 15;
  const int nr0 = (lane >> 4) << 2;
#pragma unroll
  for (int i = 0; i < 4; i++) {
    const int node = mtile * 128 + wm + i * 16 + nr0;  // m (= T col)
#pragma unroll
    for (int j = 0; j < 4; j++) {
      const int colg = ntile * 128 + wn + j * 16 + fr;  // n (= T row)
      f32x4 c = acc[i][j];
      u16x4 o;
      o.x = f2bf(2.f * c.x - (float)(node + 0 == colg));
      o.y = f2bf(2.f * c.y - (float)(node + 1 == colg));
      o.z = f2bf(2.f * c.z - (float)(node + 2 == colg));
      o.w = f2bf(2.f * c.w - (float)(node + 3 == colg));
      *(u16x4*)&Acat[(tbase + (size_t)colg) * NN + node] = o;
    }
  }
}

// ---------------- projections (MFMA) ----------------
// A-LDS [64 n][ASTRIDE kp]: staged via 4x4 register-transpose blocks
// (u16x4 global reads, u16x4 LDS writes); pad kp in [330,352) zeroed.

__device__ __forceinline__ void proj_stage(
    u16* A, const u16* __restrict__ X0, const u16* __restrict__ X1,
    const u16* __restrict__ X2, const u16* __restrict__ X3,
    const u16* __restrict__ X4, int b, int n0, int t) {
  for (int idx = t; idx < 1408; idx += 256) {  // 88 kp4-groups x 16 n4-groups
    const int kp0 = (idx >> 4) * 4;
    const int n4 = (idx & 15) * 4;
    u16x4 v[4];
#pragma unroll
    for (int r = 0; r < 4; r++) {
      const int kp = kp0 + r;
      if (kp < 330) {
        const int m = kp / 66;
        const int f = kp - m * 66;
        const u16* Xm = m == 0 ? X0 : m == 1 ? X1 : m == 2 ? X2 : m == 3 ? X3 : X4;
        v[r] = *(const u16x4*)(Xm + (size_t)(f * 64 + b) * NN + n0 + n4);
      } else {
        v[r] = u16x4{0, 0, 0, 0};
      }
    }
#pragma unroll
    for (int c = 0; c < 4; c++) {
      u16x4 o;
      o.x = v[0][c]; o.y = v[1][c]; o.z = v[2][c]; o.w = v[3][c];
      *(u16x4*)&A[(n4 + c) * ASTRIDE + kp0] = o;
    }
  }
}

// gconv1 projection: [64n x 330] @ Wt1^T -> 128 outs; sigmoid; r*hx -> X0'^T; u -> uout.
__global__ __launch_bounds__(256) void proj1(
    const u16* __restrict__ X0, const u16* __restrict__ X1, const u16* __restrict__ X2,
    const u16* __restrict__ X3, const u16* __restrict__ X4,
    const u16* __restrict__ Wt, const float* __restrict__ bias,
    const float* __restrict__ hx, u16* __restrict__ X0p, float* __restrict__ uout) {
  __shared__ u16 A[64 * ASTRIDE];
  const int t = threadIdx.x;
  const int n0 = blockIdx.x * 64;
  const int b = blockIdx.y;
  proj_stage(A, X0, X1, X2, X3, X4, b, n0, t);
  __syncthreads();

  const int lane = t & 63;
  const int w = t >> 6;
  const int fr = lane & 15;
  const int q8 = (lane >> 4) * 8;
  const u16* arow = &A[(w * 16 + fr) * ASTRIDE + q8];

  f32x4 acc[8];
#pragma unroll
  for (int j = 0; j < 8; j++) acc[j] = f32x4{0.f, 0.f, 0.f, 0.f};

  for (int kc = 0; kc < KPAD; kc += 32) {
    const s16x8 af = *(const s16x8*)(arow + kc);  // ONE b128 per k-step
#pragma unroll
    for (int j = 0; j < 8; j++) {
      const s16x8 bf = *(const s16x8*)&Wt[(size_t)(j * 16 + fr) * KPAD + kc + q8];
      acc[j] = __builtin_amdgcn_mfma_f32_16x16x32_bf16(af, bf, acc[j], 0, 0, 0);
    }
  }

  // D layout: col(o within sub) = lane&15, row(n within sub) = (lane>>4)*4 + reg
  const int nl0 = (lane >> 4) * 4;
  const int n = n0 + w * 16 + nl0;  // + reg
#pragma unroll
  for (int j = 0; j < 8; j++) {
    const int o = j * 16 + fr;
    const float bs = bias[o];
    f32x4 v;
    v.x = 1.f / (1.f + __expf(-(acc[j].x + bs)));
    v.y = 1.f / (1.f + __expf(-(acc[j].y + bs)));
    v.z = 1.f / (1.f + __expf(-(acc[j].z + bs)));
    v.w = 1.f / (1.f + __expf(-(acc[j].w + bs)));
    if (o < 64) {  // r-part -> X0'^T row (2+o)*64+b, times hx
      const float* hxp = hx + ((size_t)b << 16) + (size_t)n * 64 + o;
      u16x4 s;
      s.x = f2bf(v.x * hxp[0 * 64]);
      s.y = f2bf(v.y * hxp[1 * 64]);
      s.z = f2bf(v.z * hxp[2 * 64]);
      s.w = f2bf(v.w * hxp[3 * 64]);
      *(u16x4*)&X0p[(size_t)((2 + o) * 64 + b) * NN + n] = s;
    } else {  // u-part -> uout (d_out scratch)
      float* up = uout + (((size_t)b << 10) + n) * 64 + (o - 64);
      up[0 * 64] = v.x; up[1 * 64] = v.y; up[2 * 64] = v.z; up[3 * 64] = v.w;
    }
  }
}

// gconv2 projection: tanh + GRU blend. uin aliases out (same layout) - no restrict.
__global__ __launch_bounds__(256) void proj2(
    const u16* __restrict__ X0, const u16* __restrict__ X1, const u16* __restrict__ X2,
    const u16* __restrict__ X3, const u16* __restrict__ X4,
    const u16* __restrict__ Wt, const float* __restrict__ bias,
    const float* __restrict__ hx, const float* uin, float* out) {
  __shared__ u16 A[64 * ASTRIDE];
  const int t = threadIdx.x;
  const int n0 = blockIdx.x * 64;
  const int b = blockIdx.y;
  proj_stage(A, X0, X1, X2, X3, X4, b, n0, t);
  __syncthreads();

  const int lane = t & 63;
  const int w = t >> 6;
  const int fr = lane & 15;
  const int q8 = (lane >> 4) * 8;
  const u16* arow = &A[(w * 16 + fr) * ASTRIDE + q8];

  f32x4 acc[4];
#pragma unroll
  for (int j = 0; j < 4; j++) acc[j] = f32x4{0.f, 0.f, 0.f, 0.f};

  for (int kc = 0; kc < KPAD; kc += 32) {
    const s16x8 af = *(const s16x8*)(arow + kc);
#pragma unroll
    for (int j = 0; j < 4; j++) {
      const s16x8 bf = *(const s16x8*)&Wt[(size_t)(j * 16 + fr) * KPAD + kc + q8];
      acc[j] = __builtin_amdgcn_mfma_f32_16x16x32_bf16(af, bf, acc[j], 0, 0, 0);
    }
  }

  const int nl0 = (lane >> 4) * 4;
  const int n = n0 + w * 16 + nl0;  // + reg
#pragma unroll
  for (int j = 0; j < 4; j++) {
    const int o = j * 16 + fr;
    const float bs = bias[o];
    const size_t base = (((size_t)b << 10) + n) * 64 + o;  // + reg*64
    float c0 = tanhf(acc[j].x + bs);
    float c1 = tanhf(acc[j].y + bs);
    float c2 = tanhf(acc[j].z + bs);
    float c3 = tanhf(acc[j].w + bs);
    float u0 = uin[base + 0 * 64], u1 = uin[base + 1 * 64];
    float u2 = uin[base + 2 * 64], u3 = uin[base + 3 * 64];
    float h0 = hx[base + 0 * 64], h1 = hx[base + 1 * 64];
    float h2 = hx[base + 2 * 64], h3 = hx[base + 3 * 64];
    out[base + 0 * 64] = u0 * h0 + (1.f - u0) * c0;
    out[base + 1 * 64] = u1 * h1 + (1.f - u1) * c1;
    out[base + 2 * 64] = u2 * h2 + (1.f - u2) * c2;
    out[base + 3 * 64] = u3 * h3 + (1.f - u3) * c3;
  }
}

// ---------------- launch ----------------

extern "C" void kernel_launch(void* const* d_in, const int* in_sizes, int n_in,
                              void* d_out, int out_size, void* d_ws, size_t ws_size,
                              hipStream_t stream) {
  (void)in_sizes; (void)n_in; (void)out_size; (void)ws_size;
  const float* inp = (const float*)d_in[0];
  const float* hx  = (const float*)d_in[1];
  const float* s0  = (const float*)d_in[2];
  const float* s1  = (const float*)d_in[3];
  const float* Wo  = (const float*)d_in[4];
  const float* bo  = (const float*)d_in[5];
  const float* Wu  = (const float*)d_in[6];
  const float* bu  = (const float*)d_in[7];
  float* out = (float*)d_out;

  char* p = (char*)d_ws;
  u16* Acat = (u16*)p; p += (size_t)4096 * NN * 2;  // [S0;T0;S1;T1]
  u16* ST0  = (u16*)p; p += (size_t)NN * NN * 2;
  u16* ST1  = (u16*)p; p += (size_t)NN * NN * 2;
  const size_t xbytes = (size_t)NCOLS * NN * 2;
  u16* X0T = (u16*)p; p += xbytes;
  u16* X1T = (u16*)p; p += xbytes;
  u16* X2T = (u16*)p; p += xbytes;
  u16* X3T = (u16*)p; p += xbytes;
  u16* X4T = (u16*)p; p += xbytes;
  u16* X0P = (u16*)p; p += xbytes;
  u16* Wt1 = (u16*)p; p += (size_t)128 * KPAD * 2;
  u16* Wt2 = (u16*)p; p += (size_t)64 * KPAD * 2;
  // total ws use: 8 + 4 MB + 6*8.25 MB + ~132 KB

  pack_supports<<<dim3(256, 2), dim3(256), 0, stream>>>(s0, s1, Acat, ST0, ST1);
  sq_gemm<<<dim3(128), dim3(256), 0, stream>>>(ST0, ST1, Acat);
  pack_w<<<dim3(6, 128), dim3(64), 0, stream>>>(Wo, Wt1, 128);
  pack_w<<<dim3(6, 64), dim3(64), 0, stream>>>(Wu, Wt2, 64);
  pack_x0_inputs<<<dim3(64), dim3(256), 0, stream>>>(inp, X0T, X0P);
  pack_x0_hx<<<dim3(16, 64), dim3(256), 0, stream>>>(hx, X0T);
  // gconv1: X1=S0 X0, X2=T0 X0, X3=S1 X0, X4=T1 X0  (one launch)
  gconv_gemm<<<dim3(1056), dim3(256), 0, stream>>>(Acat, X0T, X1T, X2T, X3T, X4T);
  proj1<<<dim3(16, 64), dim3(256), 0, stream>>>(X0T, X1T, X2T, X3T, X4T, Wt1, bo, hx, X0P, out);
  // gconv2 on X0'
  gconv_gemm<<<dim3(1056), dim3(256), 0, stream>>>(Acat, X0P, X1T, X2T, X3T, X4T);
  proj2<<<dim3(16, 64), dim3(256), 0, stream>>>(X0P, X1T, X2T, X3T, X4T, Wt2, bu, hx, out, out);
}